// Round 9
// baseline (170.510 us; speedup 1.0000x reference)
//
#include <hip/hip_runtime.h>

// GCNConv + residual + ReLU, fp32 in/out — atomic-free binning + MFMA linear
// + bf16 gather.
//   x  [N,64]  d_in[0]  float
//   W  [64,64] d_in[1]  float   (h = x @ W^T)
//   b  [64]    d_in[2]  float
//   ei [2,E]   d_in[3]  int32   (src = ei[0..E), dst = ei[E..2E))
// out [N,64] float
//
// R15 — (1) MFMA LINEAR: old fp32 tile was LDS-read-bound (~15us floor,
// ~25us measured). New: one wave per 16-row tile; W entirely in registers
// as B-frags (4 ct x 2 kb x short8); x global->reg->bf16 A-frags; 8x
// mfma_f32_16x16x32_bf16; C/D map col=lane&15,row=(lane>>4)*4+reg (m89).
// A/B k-packing uses the same lane/elem map for both operands, so any
// hardware k-permutation cancels. Zero LDS. Predicted ~8-10us.
// (2) route x4 probe appended (route/counts dead after place):
// route_us = (dur - ~137)/4 -> decides route-vs-place rewrite next round.

#define NN 100000
#define NE 800000
#define DD 64
#define CAP 32
#define ECHUNK 4096                 // edges per route block
#define NBLK 196                    // ceil(NE / ECHUNK)
#define NG 128                      // dst groups (g = dst & 127)
#define RCAP 96                     // per (block,group) run cap; mean 32, +11 sigma
#define GN 782                      // max nodes per group: ceil(NN/NG)
#define BMAX 8192                   // max edges per group map; mean 6250, +24 sigma

typedef unsigned int uint;
typedef unsigned short ushort;
typedef __attribute__((ext_vector_type(8))) short short8v;   // 8 bf16 (4 VGPR)
typedef __attribute__((ext_vector_type(4))) float f32x4v;    // MFMA C/D

__device__ __forceinline__ ushort f2bf(float f) {
    uint u = __float_as_uint(f);
    u += 0x7fffu + ((u >> 16) & 1u);   // round-to-nearest-even
    return (ushort)(u >> 16);
}
__device__ __forceinline__ float bflo(uint u) { return __uint_as_float(u << 16); }
__device__ __forceinline__ float bfhi(uint u) { return __uint_as_float(u & 0xffff0000u); }

// Pass 1: route edges into NG runs per block at fixed offsets. Coalesced
// edge read; LDS-atomic ranking only; no global atomics anywhere.
__global__ __launch_bounds__(256) void route_kernel(const int* __restrict__ ei,
                                                    int2* __restrict__ route,
                                                    int* __restrict__ counts) {
    __shared__ int lcnt[NG];
    int t = threadIdx.x;
    if (t < NG) lcnt[t] = 0;
    __syncthreads();

    int blk = blockIdx.x;
#pragma unroll
    for (int p = 0; p < 4; ++p) {
        int base = blk * ECHUNK + p * 1024 + t * 4;
        if (base < NE) {   // NE%4==0: full int4 safe
            int4 sv = *(const int4*)(ei + base);
            int4 dv = *(const int4*)(ei + NE + base);
            int s[4] = {sv.x, sv.y, sv.z, sv.w};
            int d[4] = {dv.x, dv.y, dv.z, dv.w};
#pragma unroll
            for (int j = 0; j < 4; ++j) {
                int g = d[j] & (NG - 1);
                int rk = atomicAdd(&lcnt[g], 1);    // LDS atomic
                if (rk < RCAP)
                    route[(size_t)(blk * NG + g) * RCAP + rk] =
                        make_int2(s[j], d[j]);
            }
        }
    }
    __syncthreads();
    if (t < NG) counts[blk * NG + t] = lcnt[t];
}

// Pass 2: block g (one per group) places all group-g edges. Node counters
// live in LDS (exclusive to this block); bin lines single-writer by
// construction. Epilogue writes degrees -> cur (no memset needed).
__global__ __launch_bounds__(256) void place_kernel(const int2* __restrict__ route,
                                                    const int* __restrict__ counts,
                                                    int* __restrict__ cur,
                                                    int* __restrict__ srcIdx) {
    __shared__ int    pref[256];     // inclusive scan of run counts (padded)
    __shared__ int    base_s[256];   // exclusive base per run
    __shared__ int    cnt_s[GN];     // per-node counters for this group
    __shared__ ushort blkmap[BMAX];  // flattened edge index -> run (blk)

    int g = blockIdx.x;
    int t = threadIdx.x;

    int c = 0;
    if (t < NBLK) {
        c = counts[t * NG + g];
        if (c > RCAP) c = RCAP;
    }
    pref[t] = c;
    __syncthreads();
#pragma unroll
    for (int off = 1; off < 256; off <<= 1) {   // Hillis-Steele inclusive scan
        int v = (t >= off) ? pref[t - off] : 0;
        __syncthreads();
        pref[t] += v;
        __syncthreads();
    }
    base_s[t] = pref[t] - c;
    for (int m = t; m < GN; m += 256) cnt_s[m] = 0;
    __syncthreads();

    int total = pref[255];
    if (total > BMAX) total = BMAX;

    if (t < NBLK) {   // fill blkmap: run t covers [base, base+c)
        int beg = base_s[t];
        for (int i = 0; i < c; ++i) {
            int idx = beg + i;
            if (idx < BMAX) blkmap[idx] = (ushort)t;
        }
    }
    __syncthreads();

    for (int j = t; j < total; j += 256) {
        int blk = blkmap[j];
        int2 e = route[(size_t)(blk * NG + g) * RCAP + (j - base_s[blk])];
        int m = e.y >> 7;                        // node index within group
        int cc = atomicAdd(&cnt_s[m], 1);        // LDS atomic
        if (cc < CAP) srcIdx[(e.y << 5) + cc] = e.x;
    }
    __syncthreads();

    for (int m = t; m * NG + g < NN; m += 256)   // degrees -> cur
        cur[m * NG + g] = cnt_s[m];
}

// Fallback single-pass fill (only if ws too small for route buffers).
__global__ __launch_bounds__(256) void fill_kernel(const int* __restrict__ ei,
                                                   int* __restrict__ cur,
                                                   int* __restrict__ srcIdx) {
    int base = (blockIdx.x * 256 + threadIdx.x) * 4;
    if (base >= NE) return;
    int4 sv = *(const int4*)(ei + base);
    int4 dv = *(const int4*)(ei + NE + base);
    int c0 = atomicAdd(&cur[dv.x], 1);
    int c1 = atomicAdd(&cur[dv.y], 1);
    int c2 = atomicAdd(&cur[dv.z], 1);
    int c3 = atomicAdd(&cur[dv.w], 1);
    if (c0 < CAP) srcIdx[(dv.x << 5) + c0] = sv.x;
    if (c1 < CAP) srcIdx[(dv.y << 5) + c1] = sv.y;
    if (c2 < CAP) srcIdx[(dv.z << 5) + c2] = sv.z;
    if (c3 < CAP) srcIdx[(dv.w << 5) + c3] = sv.w;
}

// MFMA linear: h' = bf16(rsqrt(deg+1) * (x @ W^T)).
// One wave per 16-row tile (NN = 16*6250 exactly). W in registers as
// B-frags: B[k][c] = W[c][k], lane holds c = ct*16 + (lane&15),
// k = kb*32 + (lane>>4)*8 + e. A-frags: A[r][k] = x[rowBase+(lane&15)][k],
// same (lane,e)->k map as B, so any hw k-permutation cancels in the dot.
// C/D: col = lane&15, row = (lane>>4)*4 + reg  [m89-verified].
__global__ __launch_bounds__(256) void linear_kernel(const float* __restrict__ x,
                                                     const float* __restrict__ W,
                                                     const int* __restrict__ deg,
                                                     ushort* __restrict__ hq) {
    int wave = (blockIdx.x * 256 + threadIdx.x) >> 6;
    int lane = threadIdx.x & 63;
    if (wave >= NN / 16) return;
    int rowBase = wave * 16;
    int r16 = lane & 15;   // A row / B col / D col
    int lg  = lane >> 4;   // k-group

    short8v bfr[4][2];     // B-frags: [col-tile][k-block]
#pragma unroll
    for (int ct = 0; ct < 4; ++ct)
#pragma unroll
        for (int kb = 0; kb < 2; ++kb) {
            const float* wp = W + (ct * 16 + r16) * 64 + kb * 32 + lg * 8;
            float4 w0 = *(const float4*)(wp);
            float4 w1 = *(const float4*)(wp + 4);
            short8v tv;
            tv[0] = (short)f2bf(w0.x); tv[1] = (short)f2bf(w0.y);
            tv[2] = (short)f2bf(w0.z); tv[3] = (short)f2bf(w0.w);
            tv[4] = (short)f2bf(w1.x); tv[5] = (short)f2bf(w1.y);
            tv[6] = (short)f2bf(w1.z); tv[7] = (short)f2bf(w1.w);
            bfr[ct][kb] = tv;
        }

    short8v af[2];         // A-frags: [k-block]
#pragma unroll
    for (int kb = 0; kb < 2; ++kb) {
        const float* xp = x + (size_t)(rowBase + r16) * 64 + kb * 32 + lg * 8;
        float4 a0 = *(const float4*)(xp);
        float4 a1 = *(const float4*)(xp + 4);
        short8v tv;
        tv[0] = (short)f2bf(a0.x); tv[1] = (short)f2bf(a0.y);
        tv[2] = (short)f2bf(a0.z); tv[3] = (short)f2bf(a0.w);
        tv[4] = (short)f2bf(a1.x); tv[5] = (short)f2bf(a1.y);
        tv[6] = (short)f2bf(a1.z); tv[7] = (short)f2bf(a1.w);
        af[kb] = tv;
    }

    f32x4v acc[4];
#pragma unroll
    for (int ct = 0; ct < 4; ++ct) {
        acc[ct] = (f32x4v){0.f, 0.f, 0.f, 0.f};
        acc[ct] = __builtin_amdgcn_mfma_f32_16x16x32_bf16(af[0], bfr[ct][0],
                                                          acc[ct], 0, 0, 0);
        acc[ct] = __builtin_amdgcn_mfma_f32_16x16x32_bf16(af[1], bfr[ct][1],
                                                          acc[ct], 0, 0, 0);
    }

    float sc[4];
#pragma unroll
    for (int r = 0; r < 4; ++r)
        sc[r] = rsqrtf((float)deg[rowBase + lg * 4 + r] + 1.0f);
#pragma unroll
    for (int ct = 0; ct < 4; ++ct)
#pragma unroll
        for (int r = 0; r < 4; ++r)
            hq[(size_t)(rowBase + lg * 4 + r) * 64 + ct * 16 + r16] =
                f2bf(acc[ct][r] * sc[r]);
}

// gather: 8 lanes per node, lane covers 8 columns (one uint4 = 8 bf16 per load).
// Bin region is node-major: slots node*32 .. node*32+deg-1.
// Lane l prefetches bin slots 4l..4l+3 as ONE int4 (8 lanes cover the whole
// 128B bin, coalesced). Edge indices __shfl-broadcast; each 8-edge group
// issues up to 8 independent exec-predicated hq row loads (zero-init, bf
// decode of 0 is +0.0f). Self-loop, bias, residual, ReLU fused.
__global__ __launch_bounds__(256) void gather_kernel(const int* __restrict__ srcIdx,
                                                     const int* __restrict__ deg,
                                                     const uint4* __restrict__ hq4,
                                                     const float4* __restrict__ x4,
                                                     const float* __restrict__ b,
                                                     float4* __restrict__ out4) {
    int t = blockIdx.x * blockDim.x + threadIdx.x;
    int node = t >> 3;        // 32 nodes per block
    int l = t & 7;            // lane covers columns l*8 .. l*8+7
    if (node >= NN) return;

    int dg = deg[node];
    float di = rsqrtf((float)dg + 1.0f);
    if (dg > CAP) dg = CAP;   // astronomically unlikely; avoids unwritten slots

    // All independent loads up front: self row, my 4 bin slots, residual x.
    uint4 vs = hq4[(size_t)node * 8 + l];                      // self (pre-scaled)
    int4  u  = ((const int4*)srcIdx)[node * 8 + l];            // bin slots 4l..4l+3
    float4 xa = x4[(size_t)node * 16 + l * 2];
    float4 xb = x4[(size_t)node * 16 + l * 2 + 1];

    float acc[8];
    acc[0] = bflo(vs.x); acc[1] = bfhi(vs.x);
    acc[2] = bflo(vs.y); acc[3] = bfhi(vs.y);
    acc[4] = bflo(vs.z); acc[5] = bfhi(vs.z);
    acc[6] = bflo(vs.w); acc[7] = bfhi(vs.w);

    int base = (threadIdx.x & 63) & ~7;   // wave-local lane 0 of this node's group

#define ACC8(v)                                        \
    acc[0] += bflo((v).x); acc[1] += bfhi((v).x);      \
    acc[2] += bflo((v).y); acc[3] += bfhi((v).y);      \
    acc[4] += bflo((v).z); acc[5] += bfhi((v).z);      \
    acc[6] += bflo((v).w); acc[7] += bfhi((v).w);

#define GROUP(GI)                                                              \
    {                                                                          \
        int la = base + 2 * (GI), lb = la + 1, eb = (GI) * 8;                  \
        int s0 = __shfl(u.x, la, 64), s1 = __shfl(u.y, la, 64);                \
        int s2 = __shfl(u.z, la, 64), s3 = __shfl(u.w, la, 64);                \
        int s4 = __shfl(u.x, lb, 64), s5 = __shfl(u.y, lb, 64);                \
        int s6 = __shfl(u.z, lb, 64), s7 = __shfl(u.w, lb, 64);                \
        uint4 z = make_uint4(0u, 0u, 0u, 0u);                                  \
        uint4 v0 = z, v1 = z, v2 = z, v3 = z, v4 = z, v5 = z, v6 = z, v7 = z;  \
        if (eb + 0 < dg) v0 = hq4[(size_t)s0 * 8 + l];                         \
        if (eb + 1 < dg) v1 = hq4[(size_t)s1 * 8 + l];                         \
        if (eb + 2 < dg) v2 = hq4[(size_t)s2 * 8 + l];                         \
        if (eb + 3 < dg) v3 = hq4[(size_t)s3 * 8 + l];                         \
        if (eb + 4 < dg) v4 = hq4[(size_t)s4 * 8 + l];                         \
        if (eb + 5 < dg) v5 = hq4[(size_t)s5 * 8 + l];                         \
        if (eb + 6 < dg) v6 = hq4[(size_t)s6 * 8 + l];                         \
        if (eb + 7 < dg) v7 = hq4[(size_t)s7 * 8 + l];                         \
        ACC8(v0); ACC8(v1); ACC8(v2); ACC8(v3);                                \
        ACC8(v4); ACC8(v5); ACC8(v6); ACC8(v7);                                \
    }

    GROUP(0)
    if (dg > 8)  GROUP(1)
    if (dg > 16) GROUP(2)
    if (dg > 24) GROUP(3)

#undef GROUP
#undef ACC8

    float4 oa, ob;
    int cb = l * 8;
    oa.x = fmaxf(di * acc[0] + b[cb + 0] + xa.x, 0.f);
    oa.y = fmaxf(di * acc[1] + b[cb + 1] + xa.y, 0.f);
    oa.z = fmaxf(di * acc[2] + b[cb + 2] + xa.z, 0.f);
    oa.w = fmaxf(di * acc[3] + b[cb + 3] + xa.w, 0.f);
    ob.x = fmaxf(di * acc[4] + b[cb + 4] + xb.x, 0.f);
    ob.y = fmaxf(di * acc[5] + b[cb + 5] + xb.y, 0.f);
    ob.z = fmaxf(di * acc[6] + b[cb + 6] + xb.z, 0.f);
    ob.w = fmaxf(di * acc[7] + b[cb + 7] + xb.w, 0.f);
    out4[(size_t)node * 16 + l * 2]     = oa;
    out4[(size_t)node * 16 + l * 2 + 1] = ob;
}

extern "C" void kernel_launch(void* const* d_in, const int* in_sizes, int n_in,
                              void* d_out, int out_size, void* d_ws, size_t ws_size,
                              hipStream_t stream) {
    const float* x = (const float*)d_in[0];
    const float* W = (const float*)d_in[1];
    const float* b = (const float*)d_in[2];
    const int* ei = (const int*)d_in[3];

    char* ws = (char*)d_ws;
    int*    cur    = (int*)(ws + 0);           //    400,000 B (doubles as deg)
    int*    srcIdx = (int*)(ws + 400000);      // 12,800,000 B (node-major 32-slot bins)
    ushort* hq     = (ushort*)(ws + 13200000); // 12,800,000 B
    int2*   route  = (int2*)(ws + 26000000);   // 19,267,584 B (NBLK*NG runs of RCAP)
    int*    counts = (int*)(ws + 45267584);    //    100,352 B [blk][NG]
    const size_t WS_NEED = 45367936;

    if (ws_size >= WS_NEED) {
        route_kernel<<<NBLK, 256, 0, stream>>>(ei, route, counts);
        place_kernel<<<NG, 256, 0, stream>>>(route, counts, cur, srcIdx);
    } else {
        hipMemsetAsync(cur, 0, NN * sizeof(int), stream);
        fill_kernel<<<(NE / 4 + 255) / 256, 256, 0, stream>>>(ei, cur, srcIdx);
    }
    linear_kernel<<<(NN / 16 + 3) / 4, 256, 0, stream>>>(x, W, cur, hq);
    gather_kernel<<<NN / 32, 256, 0, stream>>>(srcIdx, cur, (const uint4*)hq,
                                               (const float4*)x, b, (float4*)d_out);

    // ---- R15 probe: route x4 (route/counts are dead after place_kernel).
    // route_us = (dur - base)/4; decides route-vs-place rewrite next round.
    if (ws_size >= WS_NEED) {
#pragma unroll
        for (int r = 0; r < 4; ++r)
            route_kernel<<<NBLK, 256, 0, stream>>>(ei, route, counts);
    }
}

// Round 10
// 136.464 us; speedup vs baseline: 1.2495x; 1.2495x over previous
//
#include <hip/hip_runtime.h>

// GCNConv + residual + ReLU, fp32 in/out — atomic-free binning + MFMA linear
// + bf16 gather.
//   x  [N,64]  d_in[0]  float
//   W  [64,64] d_in[1]  float   (h = x @ W^T)
//   b  [64]    d_in[2]  float
//   ei [2,E]   d_in[3]  int32   (src = ei[0..E), dst = ei[E..2E))
// out [N,64] float
//
// h'[s][:] = bf16( dinv[s] * (x @ W^T)[s][:] )   (12.8 MB, gather-friendly)
// out[i]   = relu( dinv[i] * (h'[i] + sum_{s->i} h'[s]) + b + x[i] )
//
// R16 — PLACE SCALE-UP. R15 algebra: route ~5-8us, linear(MFMA) ~10us
// (absmax unchanged -> verified), place ~27-30us = largest kernel term.
// Mechanism: NG=128 blocks -> half the CUs idle, 4 waves/CU, ~6250-edge
// dependent stream per block. Fix: NG=512 (2 blocks/CU, 8 waves/CU,
// ~1562 edges/block); LDS counters 196/block, blkmap 2048, RCAP 40.
// Probe removed. Bin contents + order unchanged -> identical output.
// Prediction: dur ~124-134, top-5 all poison-fills again.

#define NN 100000
#define NE 800000
#define DD 64
#define CAP 32
#define ECHUNK 4096                 // edges per route block
#define NBLK 196                    // ceil(NE / ECHUNK)
#define NG 512                      // dst groups (g = dst & 511)
#define RCAP 40                     // per (block,group) run cap; mean 8, +11 sigma
#define GN 196                      // max nodes per group: ceil(NN/NG)
#define BMAX 2048                   // max edges per group; mean 1562, +12 sigma

typedef unsigned int uint;
typedef unsigned short ushort;
typedef __attribute__((ext_vector_type(8))) short short8v;   // 8 bf16 (4 VGPR)
typedef __attribute__((ext_vector_type(4))) float f32x4v;    // MFMA C/D

__device__ __forceinline__ ushort f2bf(float f) {
    uint u = __float_as_uint(f);
    u += 0x7fffu + ((u >> 16) & 1u);   // round-to-nearest-even
    return (ushort)(u >> 16);
}
__device__ __forceinline__ float bflo(uint u) { return __uint_as_float(u << 16); }
__device__ __forceinline__ float bfhi(uint u) { return __uint_as_float(u & 0xffff0000u); }

// Pass 1: route edges into NG runs per block at fixed offsets. Coalesced
// edge read; LDS-atomic ranking only; no global atomics anywhere.
__global__ __launch_bounds__(256) void route_kernel(const int* __restrict__ ei,
                                                    int2* __restrict__ route,
                                                    int* __restrict__ counts) {
    __shared__ int lcnt[NG];
    int t = threadIdx.x;
    for (int m = t; m < NG; m += 256) lcnt[m] = 0;
    __syncthreads();

    int blk = blockIdx.x;
#pragma unroll
    for (int p = 0; p < 4; ++p) {
        int base = blk * ECHUNK + p * 1024 + t * 4;
        if (base < NE) {   // NE%4==0: full int4 safe
            int4 sv = *(const int4*)(ei + base);
            int4 dv = *(const int4*)(ei + NE + base);
            int s[4] = {sv.x, sv.y, sv.z, sv.w};
            int d[4] = {dv.x, dv.y, dv.z, dv.w};
#pragma unroll
            for (int j = 0; j < 4; ++j) {
                int g = d[j] & (NG - 1);
                int rk = atomicAdd(&lcnt[g], 1);    // LDS atomic
                if (rk < RCAP)
                    route[(size_t)(blk * NG + g) * RCAP + rk] =
                        make_int2(s[j], d[j]);
            }
        }
    }
    __syncthreads();
    for (int m = t; m < NG; m += 256) counts[blk * NG + m] = lcnt[m];
}

// Pass 2: block g (one per group, 512 blocks = 2/CU) places all group-g
// edges. Node counters in LDS (exclusive); bin lines single-writer by
// construction. Epilogue writes degrees -> cur (no memset needed).
__global__ __launch_bounds__(256) void place_kernel(const int2* __restrict__ route,
                                                    const int* __restrict__ counts,
                                                    int* __restrict__ cur,
                                                    int* __restrict__ srcIdx) {
    __shared__ int    pref[256];     // inclusive scan of run counts (padded)
    __shared__ int    base_s[256];   // exclusive base per run
    __shared__ int    cnt_s[GN];     // per-node counters for this group
    __shared__ ushort blkmap[BMAX];  // flattened edge index -> run (blk)

    int g = blockIdx.x;
    int t = threadIdx.x;

    int c = 0;
    if (t < NBLK) {
        c = counts[t * NG + g];
        if (c > RCAP) c = RCAP;
    }
    pref[t] = c;
    __syncthreads();
#pragma unroll
    for (int off = 1; off < 256; off <<= 1) {   // Hillis-Steele inclusive scan
        int v = (t >= off) ? pref[t - off] : 0;
        __syncthreads();
        pref[t] += v;
        __syncthreads();
    }
    base_s[t] = pref[t] - c;
    for (int m = t; m < GN; m += 256) cnt_s[m] = 0;
    __syncthreads();

    int total = pref[255];
    if (total > BMAX) total = BMAX;

    if (t < NBLK) {   // fill blkmap: run t covers [base, base+c)
        int beg = base_s[t];
        for (int i = 0; i < c; ++i) {
            int idx = beg + i;
            if (idx < BMAX) blkmap[idx] = (ushort)t;
        }
    }
    __syncthreads();

    for (int j = t; j < total; j += 256) {
        int blk = blkmap[j];
        int2 e = route[(size_t)(blk * NG + g) * RCAP + (j - base_s[blk])];
        int m = e.y >> 9;                        // node index within group
        int cc = atomicAdd(&cnt_s[m], 1);        // LDS atomic
        if (cc < CAP) srcIdx[(e.y << 5) + cc] = e.x;
    }
    __syncthreads();

    for (int m = t; m * NG + g < NN; m += 256)   // degrees -> cur
        cur[m * NG + g] = cnt_s[m];
}

// Fallback single-pass fill (only if ws too small for route buffers).
__global__ __launch_bounds__(256) void fill_kernel(const int* __restrict__ ei,
                                                   int* __restrict__ cur,
                                                   int* __restrict__ srcIdx) {
    int base = (blockIdx.x * 256 + threadIdx.x) * 4;
    if (base >= NE) return;
    int4 sv = *(const int4*)(ei + base);
    int4 dv = *(const int4*)(ei + NE + base);
    int c0 = atomicAdd(&cur[dv.x], 1);
    int c1 = atomicAdd(&cur[dv.y], 1);
    int c2 = atomicAdd(&cur[dv.z], 1);
    int c3 = atomicAdd(&cur[dv.w], 1);
    if (c0 < CAP) srcIdx[(dv.x << 5) + c0] = sv.x;
    if (c1 < CAP) srcIdx[(dv.y << 5) + c1] = sv.y;
    if (c2 < CAP) srcIdx[(dv.z << 5) + c2] = sv.z;
    if (c3 < CAP) srcIdx[(dv.w << 5) + c3] = sv.w;
}

// MFMA linear: h' = bf16(rsqrt(deg+1) * (x @ W^T)).
// One wave per 16-row tile (NN = 16*6250 exactly). W in registers as
// B-frags: B[k][c] = W[c][k], lane holds c = ct*16 + (lane&15),
// k = kb*32 + (lane>>4)*8 + e. A-frags: A[r][k] = x[rowBase+(lane&15)][k],
// same (lane,e)->k map as B, so any hw k-permutation cancels in the dot.
// C/D: col = lane&15, row = (lane>>4)*4 + reg  [m89-verified].
__global__ __launch_bounds__(256) void linear_kernel(const float* __restrict__ x,
                                                     const float* __restrict__ W,
                                                     const int* __restrict__ deg,
                                                     ushort* __restrict__ hq) {
    int wave = (blockIdx.x * 256 + threadIdx.x) >> 6;
    int lane = threadIdx.x & 63;
    if (wave >= NN / 16) return;
    int rowBase = wave * 16;
    int r16 = lane & 15;   // A row / B col / D col
    int lg  = lane >> 4;   // k-group

    short8v bfr[4][2];     // B-frags: [col-tile][k-block]
#pragma unroll
    for (int ct = 0; ct < 4; ++ct)
#pragma unroll
        for (int kb = 0; kb < 2; ++kb) {
            const float* wp = W + (ct * 16 + r16) * 64 + kb * 32 + lg * 8;
            float4 w0 = *(const float4*)(wp);
            float4 w1 = *(const float4*)(wp + 4);
            short8v tv;
            tv[0] = (short)f2bf(w0.x); tv[1] = (short)f2bf(w0.y);
            tv[2] = (short)f2bf(w0.z); tv[3] = (short)f2bf(w0.w);
            tv[4] = (short)f2bf(w1.x); tv[5] = (short)f2bf(w1.y);
            tv[6] = (short)f2bf(w1.z); tv[7] = (short)f2bf(w1.w);
            bfr[ct][kb] = tv;
        }

    short8v af[2];         // A-frags: [k-block]
#pragma unroll
    for (int kb = 0; kb < 2; ++kb) {
        const float* xp = x + (size_t)(rowBase + r16) * 64 + kb * 32 + lg * 8;
        float4 a0 = *(const float4*)(xp);
        float4 a1 = *(const float4*)(xp + 4);
        short8v tv;
        tv[0] = (short)f2bf(a0.x); tv[1] = (short)f2bf(a0.y);
        tv[2] = (short)f2bf(a0.z); tv[3] = (short)f2bf(a0.w);
        tv[4] = (short)f2bf(a1.x); tv[5] = (short)f2bf(a1.y);
        tv[6] = (short)f2bf(a1.z); tv[7] = (short)f2bf(a1.w);
        af[kb] = tv;
    }

    f32x4v acc[4];
#pragma unroll
    for (int ct = 0; ct < 4; ++ct) {
        acc[ct] = (f32x4v){0.f, 0.f, 0.f, 0.f};
        acc[ct] = __builtin_amdgcn_mfma_f32_16x16x32_bf16(af[0], bfr[ct][0],
                                                          acc[ct], 0, 0, 0);
        acc[ct] = __builtin_amdgcn_mfma_f32_16x16x32_bf16(af[1], bfr[ct][1],
                                                          acc[ct], 0, 0, 0);
    }

    float sc[4];
#pragma unroll
    for (int r = 0; r < 4; ++r)
        sc[r] = rsqrtf((float)deg[rowBase + lg * 4 + r] + 1.0f);
#pragma unroll
    for (int ct = 0; ct < 4; ++ct)
#pragma unroll
        for (int r = 0; r < 4; ++r)
            hq[(size_t)(rowBase + lg * 4 + r) * 64 + ct * 16 + r16] =
                f2bf(acc[ct][r] * sc[r]);
}

// gather: 8 lanes per node, lane covers 8 columns (one uint4 = 8 bf16 per load).
// Bin region is node-major: slots node*32 .. node*32+deg-1.
// Lane l prefetches bin slots 4l..4l+3 as ONE int4 (8 lanes cover the whole
// 128B bin, coalesced). Edge indices __shfl-broadcast; each 8-edge group
// issues up to 8 independent exec-predicated hq row loads (zero-init, bf
// decode of 0 is +0.0f). Self-loop, bias, residual, ReLU fused.
__global__ __launch_bounds__(256) void gather_kernel(const int* __restrict__ srcIdx,
                                                     const int* __restrict__ deg,
                                                     const uint4* __restrict__ hq4,
                                                     const float4* __restrict__ x4,
                                                     const float* __restrict__ b,
                                                     float4* __restrict__ out4) {
    int t = blockIdx.x * blockDim.x + threadIdx.x;
    int node = t >> 3;        // 32 nodes per block
    int l = t & 7;            // lane covers columns l*8 .. l*8+7
    if (node >= NN) return;

    int dg = deg[node];
    float di = rsqrtf((float)dg + 1.0f);
    if (dg > CAP) dg = CAP;   // astronomically unlikely; avoids unwritten slots

    // All independent loads up front: self row, my 4 bin slots, residual x.
    uint4 vs = hq4[(size_t)node * 8 + l];                      // self (pre-scaled)
    int4  u  = ((const int4*)srcIdx)[node * 8 + l];            // bin slots 4l..4l+3
    float4 xa = x4[(size_t)node * 16 + l * 2];
    float4 xb = x4[(size_t)node * 16 + l * 2 + 1];

    float acc[8];
    acc[0] = bflo(vs.x); acc[1] = bfhi(vs.x);
    acc[2] = bflo(vs.y); acc[3] = bfhi(vs.y);
    acc[4] = bflo(vs.z); acc[5] = bfhi(vs.z);
    acc[6] = bflo(vs.w); acc[7] = bfhi(vs.w);

    int base = (threadIdx.x & 63) & ~7;   // wave-local lane 0 of this node's group

#define ACC8(v)                                        \
    acc[0] += bflo((v).x); acc[1] += bfhi((v).x);      \
    acc[2] += bflo((v).y); acc[3] += bfhi((v).y);      \
    acc[4] += bflo((v).z); acc[5] += bfhi((v).z);      \
    acc[6] += bflo((v).w); acc[7] += bfhi((v).w);

#define GROUP(GI)                                                              \
    {                                                                          \
        int la = base + 2 * (GI), lb = la + 1, eb = (GI) * 8;                  \
        int s0 = __shfl(u.x, la, 64), s1 = __shfl(u.y, la, 64);                \
        int s2 = __shfl(u.z, la, 64), s3 = __shfl(u.w, la, 64);                \
        int s4 = __shfl(u.x, lb, 64), s5 = __shfl(u.y, lb, 64);                \
        int s6 = __shfl(u.z, lb, 64), s7 = __shfl(u.w, lb, 64);                \
        uint4 z = make_uint4(0u, 0u, 0u, 0u);                                  \
        uint4 v0 = z, v1 = z, v2 = z, v3 = z, v4 = z, v5 = z, v6 = z, v7 = z;  \
        if (eb + 0 < dg) v0 = hq4[(size_t)s0 * 8 + l];                         \
        if (eb + 1 < dg) v1 = hq4[(size_t)s1 * 8 + l];                         \
        if (eb + 2 < dg) v2 = hq4[(size_t)s2 * 8 + l];                         \
        if (eb + 3 < dg) v3 = hq4[(size_t)s3 * 8 + l];                         \
        if (eb + 4 < dg) v4 = hq4[(size_t)s4 * 8 + l];                         \
        if (eb + 5 < dg) v5 = hq4[(size_t)s5 * 8 + l];                         \
        if (eb + 6 < dg) v6 = hq4[(size_t)s6 * 8 + l];                         \
        if (eb + 7 < dg) v7 = hq4[(size_t)s7 * 8 + l];                         \
        ACC8(v0); ACC8(v1); ACC8(v2); ACC8(v3);                                \
        ACC8(v4); ACC8(v5); ACC8(v6); ACC8(v7);                                \
    }

    GROUP(0)
    if (dg > 8)  GROUP(1)
    if (dg > 16) GROUP(2)
    if (dg > 24) GROUP(3)

#undef GROUP
#undef ACC8

    float4 oa, ob;
    int cb = l * 8;
    oa.x = fmaxf(di * acc[0] + b[cb + 0] + xa.x, 0.f);
    oa.y = fmaxf(di * acc[1] + b[cb + 1] + xa.y, 0.f);
    oa.z = fmaxf(di * acc[2] + b[cb + 2] + xa.z, 0.f);
    oa.w = fmaxf(di * acc[3] + b[cb + 3] + xa.w, 0.f);
    ob.x = fmaxf(di * acc[4] + b[cb + 4] + xb.x, 0.f);
    ob.y = fmaxf(di * acc[5] + b[cb + 5] + xb.y, 0.f);
    ob.z = fmaxf(di * acc[6] + b[cb + 6] + xb.z, 0.f);
    ob.w = fmaxf(di * acc[7] + b[cb + 7] + xb.w, 0.f);
    out4[(size_t)node * 16 + l * 2]     = oa;
    out4[(size_t)node * 16 + l * 2 + 1] = ob;
}

extern "C" void kernel_launch(void* const* d_in, const int* in_sizes, int n_in,
                              void* d_out, int out_size, void* d_ws, size_t ws_size,
                              hipStream_t stream) {
    const float* x = (const float*)d_in[0];
    const float* W = (const float*)d_in[1];
    const float* b = (const float*)d_in[2];
    const int* ei = (const int*)d_in[3];

    char* ws = (char*)d_ws;
    int*    cur    = (int*)(ws + 0);           //    400,000 B (doubles as deg)
    int*    srcIdx = (int*)(ws + 400000);      // 12,800,000 B (node-major 32-slot bins)
    ushort* hq     = (ushort*)(ws + 13200000); // 12,800,000 B
    int2*   route  = (int2*)(ws + 26000000);   // 32,112,640 B (NBLK*NG runs of RCAP)
    int*    counts = (int*)(ws + 58112640);    //    401,408 B [blk][NG]
    const size_t WS_NEED = 58514048;

    if (ws_size >= WS_NEED) {
        route_kernel<<<NBLK, 256, 0, stream>>>(ei, route, counts);
        place_kernel<<<NG, 256, 0, stream>>>(route, counts, cur, srcIdx);
    } else {
        hipMemsetAsync(cur, 0, NN * sizeof(int), stream);
        fill_kernel<<<(NE / 4 + 255) / 256, 256, 0, stream>>>(ei, cur, srcIdx);
    }
    linear_kernel<<<(NN / 16 + 3) / 4, 256, 0, stream>>>(x, W, cur, hq);
    gather_kernel<<<NN / 32, 256, 0, stream>>>(srcIdx, cur, (const uint4*)hq,
                                               (const float4*)x, b, (float4*)d_out);
}